// Round 5
// baseline (4621.529 us; speedup 1.0000x reference)
//
#include <hip/hip_runtime.h>

#define B_    64
#define L1C   4093
#define L2C   4086
#define L3C   4071
#define TDEC  60

static __device__ __forceinline__ float sigf(float x){ return 1.f/(1.f + __expf(-x)); }
static __device__ __forceinline__ unsigned f2bf(float f){
  unsigned u = __float_as_uint(f);
  u = u + 0x7fffu + ((u >> 16) & 1u);   // RNE to bf16
  return (u >> 16);
}
static __device__ __forceinline__ float bfl(unsigned u){ return __uint_as_float(u<<16); }
static __device__ __forceinline__ float bfh(unsigned u){ return __uint_as_float(u & 0xffff0000u); }

// ---------------- conv stack ----------------
template<int CIN,int COUT,int KW,bool BF16OUT>
__global__ __launch_bounds__(256) void k_conv(
    const float* __restrict__ in, const float* __restrict__ w,
    const float* __restrict__ bias, void* __restrict__ outp,
    int Lin_, int Lout_)
{
  int g = blockIdx.x*256 + threadIdx.x;
  int bi = g / Lout_;
  int l  = g - bi*Lout_;
  if (bi >= B_) return;
  float acc[COUT];
#pragma unroll
  for (int o=0;o<COUT;o++) acc[o] = bias[o];
  const float* ip = in + ((size_t)bi*Lin_ + l)*CIN;
  for (int k=0;k<KW;k++){
#pragma unroll
    for (int i4=0;i4<CIN/4;i4++){
      float4 xv = *(const float4*)(ip + k*CIN + i4*4);
#pragma unroll
      for (int c=0;c<4;c++){
        float xs = (&xv.x)[c];
        int i = i4*4+c;
#pragma unroll
        for (int o=0;o<COUT;o++)
          acc[o] = fmaf(xs, w[(o*CIN + i)*KW + k], acc[o]);
      }
    }
  }
  if constexpr (BF16OUT){
    unsigned* op = (unsigned*)outp + ((size_t)bi*Lout_ + l)*(COUT/2);
#pragma unroll
    for (int o2=0;o2<COUT/2;o2++){
      unsigned lo = f2bf(fmaxf(acc[2*o2],0.f));
      unsigned hi = f2bf(fmaxf(acc[2*o2+1],0.f));
      op[o2] = lo | (hi<<16);
    }
  } else {
    float* op = (float*)outp + ((size_t)bi*Lout_ + l)*COUT;
#pragma unroll
    for (int o=0;o<COUT;o++) op[o] = fmaxf(acc[o],0.f);
  }
}

// ---------------- pack weights: [2][1024][K] fp32 -> [2][K/8][1024] bf16x8 ----------------
__global__ __launch_bounds__(256) void k_packw2(
    const float* __restrict__ w, uint4* __restrict__ wT, int K)
{
  int gid = blockIdx.x*256 + threadIdx.x;
  int per = (K/8)*1024;
  int d = gid / per, rem = gid - d*per;
  int j8 = rem >> 10, row = rem & 1023;
  const float* src = w + ((size_t)d*1024 + row)*K + j8*8;
  float4 a = *(const float4*)src;
  float4 b = *(const float4*)(src+4);
  uint4 o;
  o.x = f2bf(a.x) | (f2bf(a.y)<<16);
  o.y = f2bf(a.z) | (f2bf(a.w)<<16);
  o.z = f2bf(b.x) | (f2bf(b.y)<<16);
  o.w = f2bf(b.z) | (f2bf(b.w)<<16);
  wT[gid] = o;
}

#define ACC8(eu, base) \
  s = fmaf(bfl(eu.x), vl[(base)+0], s); s = fmaf(bfh(eu.x), vl[(base)+1], s); \
  s = fmaf(bfl(eu.y), vl[(base)+2], s); s = fmaf(bfh(eu.y), vl[(base)+3], s); \
  s = fmaf(bfl(eu.z), vl[(base)+4], s); s = fmaf(bfh(eu.z), vl[(base)+5], s); \
  s = fmaf(bfl(eu.w), vl[(base)+6], s); s = fmaf(bfh(eu.w), vl[(base)+7], s);

// ---------------- dec1: block = (d,b), fully block-local, no grid sync ----------------
// 128 blocks x 1024 threads; h/c/softmax state in LDS/regs; enc+whh streamed from L2.
__global__ __launch_bounds__(1024) void k_dec1b(
    const unsigned* __restrict__ enc,      // [B][L3C][16] uints (bf16 pairs, 32 ch)
    const float* __restrict__ attn_w,      // [256][32]
    const uint4* __restrict__ wihT,        // [2][4][1024] bf16x8 (K=32)
    const uint4* __restrict__ whhT,        // [2][32][1024] bf16x8 (K=256)
    const float* __restrict__ bih, const float* __restrict__ bhh,
    float* __restrict__ d2in)              // [B][60][512]
{
  int b = blockIdx.x, d = blockIdx.y, tid = threadIdx.x;
  __shared__ float hls[256];
  __shared__ float vl[32];
  __shared__ float e_l[4096];
  __shared__ float red[1024];
  __shared__ float scr[2048];
  __shared__ float ctx[32];
  __shared__ float gls[1024];

  if (tid < 256) hls[tid] = 0.f;
  float creg = 0.f;
  float bsum = bih[(size_t)d*1024 + tid] + bhh[(size_t)d*1024 + tid];
  uint4 wpre[4];
#pragma unroll
  for (int c8=0;c8<4;c8++) wpre[c8] = wihT[(size_t)d*4096 + c8*1024 + tid];
  const uint4* whp = whhT + (size_t)d*32768;
  const unsigned* encb = enc + (size_t)b*L3C*16;
  __syncthreads();

  for (int t=0; t<TDEC; t++){
    // -- phase 1: v[c] = sum_u h[u]*attn_w[u][c] --
    {
      int c = tid & 31, part = tid >> 5;            // 32 parts x 8 u
      const float* wp = attn_w + (size_t)(part*8)*32 + c;
      float s = 0.f;
#pragma unroll
      for (int k=0;k<8;k++) s = fmaf(hls[part*8+k], wp[k*32], s);
      red[tid] = s;
    }
    __syncthreads();                                 // (A)
    if (tid < 32){
      float v = 0.f;
#pragma unroll
      for (int p=0;p<32;p++) v += red[p*32 + tid];
      vl[tid] = v;
    }
    __syncthreads();                                 // (B)

    // -- phase 2: scores + online softmax --
    float al[4];
#pragma unroll
    for (int k=0;k<4;k++){
      int l = tid + k*1024;
      float s = 0.f;
      if (l < L3C){
        const uint4* ep = (const uint4*)(encb + (size_t)l*16);
        uint4 e0 = ep[0], e1 = ep[1], e2 = ep[2], e3 = ep[3];
        ACC8(e0, 0) ACC8(e1, 8) ACC8(e2, 16) ACC8(e3, 24)
      }
      al[k] = (l < L3C) ? s : -3.0e38f;
    }
    float m = fmaxf(fmaxf(al[0],al[1]), fmaxf(al[2],al[3]));
#pragma unroll
    for (int off=32; off; off>>=1) m = fmaxf(m, __shfl_xor(m, off));
    if ((tid&63)==0) red[tid>>6] = m;                // 16 wave maxes
    __syncthreads();                                 // (C)
    m = red[0];
#pragma unroll
    for (int i=1;i<16;i++) m = fmaxf(m, red[i]);
    float ssum = 0.f;
#pragma unroll
    for (int k=0;k<4;k++){
      int l = tid + k*1024;
      float e = (l < L3C) ? __expf(al[k]-m) : 0.f;
      e_l[l] = e;
      ssum += e;
    }
#pragma unroll
    for (int off=32; off; off>>=1) ssum += __shfl_xor(ssum, off);
    if ((tid&63)==0) red[16 + (tid>>6)] = ssum;
    __syncthreads();                                 // (D)

    // -- phase 3: ctx numerator --
    {
      int c2 = tid & 15, grp = tid >> 4;             // 64 groups
      float a0=0.f, a1=0.f;
      for (int l=grp; l<4096; l+=64){
        float e = e_l[l];
        unsigned u = (l < L3C) ? encb[(size_t)l*16 + c2] : 0u;
        a0 = fmaf(e, bfl(u), a0);
        a1 = fmaf(e, bfh(u), a1);
      }
      scr[(grp*16 + c2)*2 + 0] = a0;
      scr[(grp*16 + c2)*2 + 1] = a1;
    }
    __syncthreads();                                 // (E)
    if (tid < 32){
      float S = red[16];
#pragma unroll
      for (int i=17;i<32;i++) S += red[i];
      float s2 = 0.f;
      int cc2 = tid>>1, comp = tid&1;
#pragma unroll
      for (int g=0;g<64;g++) s2 += scr[(g*16 + cc2)*2 + comp];
      ctx[tid] = s2 / S;
    }
    __syncthreads();                                 // (F)

    // -- phase 4: LSTM gates (row = tid) --
    float g = bsum;
#pragma unroll
    for (int c8=0;c8<4;c8++){
      uint4 wv = wpre[c8];
      float4 x0 = *(const float4*)&ctx[c8*8];
      float4 x1 = *(const float4*)&ctx[c8*8+4];
      g = fmaf(bfl(wv.x), x0.x, g); g = fmaf(bfh(wv.x), x0.y, g);
      g = fmaf(bfl(wv.y), x0.z, g); g = fmaf(bfh(wv.y), x0.w, g);
      g = fmaf(bfl(wv.z), x1.x, g); g = fmaf(bfh(wv.z), x1.y, g);
      g = fmaf(bfl(wv.w), x1.z, g); g = fmaf(bfh(wv.w), x1.w, g);
    }
#pragma unroll 4
    for (int j8=0;j8<32;j8++){
      uint4 wv = whp[j8*1024 + tid];
      float4 h0 = *(const float4*)&hls[j8*8];
      float4 h1 = *(const float4*)&hls[j8*8+4];
      g = fmaf(bfl(wv.x), h0.x, g); g = fmaf(bfh(wv.x), h0.y, g);
      g = fmaf(bfl(wv.y), h0.z, g); g = fmaf(bfh(wv.y), h0.w, g);
      g = fmaf(bfl(wv.z), h1.x, g); g = fmaf(bfh(wv.z), h1.y, g);
      g = fmaf(bfl(wv.w), h1.z, g); g = fmaf(bfh(wv.w), h1.w, g);
    }
    gls[tid] = g;
    __syncthreads();                                 // (G)
    if (tid < 256){
      float ii = sigf(gls[tid]);
      float ff = sigf(gls[256+tid]);
      float gg = tanhf(gls[512+tid]);
      float oo = sigf(gls[768+tid]);
      creg = fmaf(ff, creg, ii*gg);
      float hn = oo * tanhf(creg);
      hls[tid] = hn;
      int tout = d ? (59 - t) : t;
      d2in[((size_t)b*60 + tout)*512 + d*256 + tid] = hn;
    }
    __syncthreads();                                 // (H)
  }
}

// ---------------- generic fp32 GEMM ----------------
__global__ __launch_bounds__(256) void k_gemm(
    const float* __restrict__ A, const float* __restrict__ W,
    float* __restrict__ C, const float* __restrict__ b1, const float* __restrict__ b2,
    int K, int ldc, size_t sW, size_t sC, int sB)
{
  int m0 = blockIdx.x * 128, n0 = blockIdx.y * 128, z = blockIdx.z;
  const float* Wz = W + (size_t)z*sW;
  float* Cz = C + (size_t)z*sC;
  const float* b1z = b1 + (size_t)z*sB;
  const float* b2z = b2 ? (b2 + (size_t)z*sB) : nullptr;
  __shared__ __align__(16) float As[16][132];
  __shared__ __align__(16) float Bs[16][132];
  int tid = threadIdx.x;
  int tx = tid & 15, ty = tid >> 4;
  int r = tid >> 2, c4 = tid & 3;
  float acc[8][8] = {};
  for (int k0=0; k0<K; k0+=16){
#pragma unroll
    for (int h=0; h<2; h++){
      int rr = r + h*64;
      float4 av = *(const float4*)(A  + (size_t)(m0+rr)*K + k0 + c4*4);
      float4 bv = *(const float4*)(Wz + (size_t)(n0+rr)*K + k0 + c4*4);
      As[c4*4+0][rr]=av.x; As[c4*4+1][rr]=av.y; As[c4*4+2][rr]=av.z; As[c4*4+3][rr]=av.w;
      Bs[c4*4+0][rr]=bv.x; Bs[c4*4+1][rr]=bv.y; Bs[c4*4+2][rr]=bv.z; Bs[c4*4+3][rr]=bv.w;
    }
    __syncthreads();
#pragma unroll
    for (int kk=0; kk<16; kk++){
      float a[8], bb[8];
      *(float4*)&a[0]  = *(const float4*)&As[kk][ty*8];
      *(float4*)&a[4]  = *(const float4*)&As[kk][ty*8+4];
      *(float4*)&bb[0] = *(const float4*)&Bs[kk][tx*8];
      *(float4*)&bb[4] = *(const float4*)&Bs[kk][tx*8+4];
#pragma unroll
      for (int i=0;i<8;i++)
#pragma unroll
        for (int j=0;j<8;j++)
          acc[i][j] = fmaf(a[i], bb[j], acc[i][j]);
    }
    __syncthreads();
  }
  float bb1[8];
#pragma unroll
  for (int j=0;j<8;j++){
    int n = n0 + tx*8 + j;
    bb1[j] = b1z[n] + (b2z ? b2z[n] : 0.f);
  }
#pragma unroll
  for (int i=0;i<8;i++){
    int m = m0 + ty*8 + i;
    float o[8];
#pragma unroll
    for (int j=0;j<8;j++) o[j] = acc[i][j] + bb1[j];
    *(float4*)(Cz + (size_t)m*ldc + n0 + tx*8)     = *(const float4*)&o[0];
    *(float4*)(Cz + (size_t)m*ldc + n0 + tx*8 + 4) = *(const float4*)&o[4];
  }
}

// ---------------- dec2: recurrent, block = (dir, batch), 16 waves ----------------
__global__ __launch_bounds__(1024) void k_rec2(
    const float* __restrict__ xg,   // [2][64][60][1024]
    const uint4* __restrict__ wT,   // [2][32][1024] bf16x8
    float* __restrict__ out)        // [64][60][512]
{
  int b = blockIdx.x, d = blockIdx.y, tid = threadIdx.x;
  __shared__ __align__(16) float hls[256];
  __shared__ float gls[1024];
  float c = 0.f;
  if (tid < 256) hls[tid] = 0.f;
  __syncthreads();
  const uint4* wp = wT + (size_t)d*32*1024;
  const float* xp = xg + (((size_t)d*64 + b)*60)*1024;
  for (int step=0; step<TDEC; step++){
    int t = d ? (TDEC-1-step) : step;
    float g = xp[(size_t)t*1024 + tid];
#pragma unroll 4
    for (int j8=0;j8<32;j8++){
      uint4 wv = wp[j8*1024 + tid];
      float4 h0 = *(const float4*)&hls[j8*8];
      float4 h1 = *(const float4*)&hls[j8*8+4];
      g = fmaf(bfl(wv.x), h0.x, g); g = fmaf(bfh(wv.x), h0.y, g);
      g = fmaf(bfl(wv.y), h0.z, g); g = fmaf(bfh(wv.y), h0.w, g);
      g = fmaf(bfl(wv.z), h1.x, g); g = fmaf(bfh(wv.z), h1.y, g);
      g = fmaf(bfl(wv.w), h1.z, g); g = fmaf(bfh(wv.w), h1.w, g);
    }
    gls[tid] = g;
    __syncthreads();
    if (tid < 256){
      float ii = sigf(gls[tid]);
      float ff = sigf(gls[256+tid]);
      float gg = tanhf(gls[512+tid]);
      float oo = sigf(gls[768+tid]);
      c = fmaf(ff, c, ii*gg);
      float hn = oo * tanhf(c);
      hls[tid] = hn;
      out[((size_t)b*60 + t)*512 + d*256 + tid] = hn;
    }
    __syncthreads();
  }
}

extern "C" void kernel_launch(void* const* d_in, const int* in_sizes, int n_in,
                              void* d_out, int out_size, void* d_ws, size_t ws_size,
                              hipStream_t stream) {
  const float* x      = (const float*)d_in[0];
  const float* cw1    = (const float*)d_in[1];
  const float* cb1    = (const float*)d_in[2];
  const float* cw2    = (const float*)d_in[3];
  const float* cb2    = (const float*)d_in[4];
  const float* cw3    = (const float*)d_in[5];
  const float* cb3    = (const float*)d_in[6];
  const float* attn_w = (const float*)d_in[7];
  // d_in[8] attn_b: constant over softmax axis -> drops out analytically
  const float* d1_wih = (const float*)d_in[9];
  const float* d1_whh = (const float*)d_in[10];
  const float* d1_bih = (const float*)d_in[11];
  const float* d1_bhh = (const float*)d_in[12];
  const float* w2_ih0 = (const float*)d_in[13];
  const float* w2_hh0 = (const float*)d_in[14];
  const float* b2_ih0 = (const float*)d_in[15];
  const float* b2_hh0 = (const float*)d_in[16];
  const float* w2_ih1 = (const float*)d_in[17];
  const float* w2_hh1 = (const float*)d_in[18];
  const float* b2_ih1 = (const float*)d_in[19];
  const float* b2_hh1 = (const float*)d_in[20];
  const float* out_w  = (const float*)d_in[21];
  const float* out_b  = (const float*)d_in[22];

  char* ws = (char*)d_ws;
  size_t off = 0;
  unsigned* enc = (unsigned*)(ws + off); off += 16675840;          // bf16 enc, padded
  size_t off_h1 = off;
  float* h1buf = (float*)(ws + off); off += 8382464;               // (B,4093,8)
  float* h2buf = (float*)(ws + off); off += 16736256;              // (B,4086,16)
  float* d2in  = (float*)(ws + off_h1);                            // reuse: (B,60,512)
  float* l0    = (float*)(ws + off_h1 + 7864320);
  float* l1    = (float*)(ws + off_h1 + 15728640);
  uint4* wT    = (uint4*)(ws + off_h1 + 23592960);                 // 1MB dec2 pack (dead tail)
  float* xg    = (float*)(ws + off); off += 31457280;              // [2][B][60][1024]
  // dec1 packs live INSIDE the xg region (xg written only after dec1 completes)
  uint4* d1whhT = (uint4*)xg;                                      // 1 MB
  uint4* d1wihT = (uint4*)(ws + (size_t)(xg - (float*)ws)*4 + 1048576); // +128 KB
  (void)ws_size; (void)in_sizes; (void)n_in; (void)out_size;

  // dec1 weight packs (before dec1; clobbered later by xg — fine)
  k_packw2<<<256,256,0,stream>>>(d1_whh, d1whhT, 256);
  k_packw2<<<32, 256,0,stream>>>(d1_wih, d1wihT, 32);

  int g1 = (B_*L1C + 255)/256;
  k_conv<64,8,4,false><<<g1,256,0,stream>>>(x, cw1, cb1, h1buf, 4096, L1C);
  int g2 = (B_*L2C + 255)/256;
  k_conv<8,16,8,false><<<g2,256,0,stream>>>(h1buf, cw2, cb2, h2buf, L1C, L2C);
  int g3 = (B_*L3C + 255)/256;
  k_conv<16,32,16,true><<<g3,256,0,stream>>>(h2buf, cw3, cb3, enc, L2C, L3C);

  // dec1: one plain launch, block=(d,b), no inter-block sync of any kind
  k_dec1b<<<dim3(64,2),1024,0,stream>>>(enc, attn_w, d1wihT, d1whhT,
                                        d1_bih, d1_bhh, d2in);

  // dec2 layer 0
  k_packw2<<<256,256,0,stream>>>(w2_hh0, wT, 256);
  k_gemm<<<dim3(30,8,2),256,0,stream>>>(d2in, w2_ih0, xg, b2_ih0, b2_hh0,
                                        512, 1024, (size_t)1024*512, (size_t)3840*1024, 1024);
  k_rec2<<<dim3(64,2),1024,0,stream>>>(xg, wT, l0);
  // dec2 layer 1
  k_packw2<<<256,256,0,stream>>>(w2_hh1, wT, 256);
  k_gemm<<<dim3(30,8,2),256,0,stream>>>(l0, w2_ih1, xg, b2_ih1, b2_hh1,
                                        512, 1024, (size_t)1024*512, (size_t)3840*1024, 1024);
  k_rec2<<<dim3(64,2),1024,0,stream>>>(xg, wT, l1);
  // output projection
  k_gemm<<<dim3(30,1,1),256,0,stream>>>(l1, out_w, (float*)d_out, out_b, nullptr,
                                        512, 128, 0, 0, 0);
}

// Round 6
// 4144.539 us; speedup vs baseline: 1.1151x; 1.1151x over previous
//
#include <hip/hip_runtime.h>

#define B_    64
#define L1C   4093
#define L2C   4086
#define L3C   4071
#define TDEC  60

static __device__ __forceinline__ float sigf(float x){ return 1.f/(1.f + __expf(-x)); }
static __device__ __forceinline__ unsigned f2bf(float f){
  unsigned u = __float_as_uint(f);
  u = u + 0x7fffu + ((u >> 16) & 1u);   // RNE to bf16
  return (u >> 16);
}
static __device__ __forceinline__ float bfl(unsigned u){ return __uint_as_float(u<<16); }
static __device__ __forceinline__ float bfh(unsigned u){ return __uint_as_float(u & 0xffff0000u); }

// ---------------- conv stack ----------------
template<int CIN,int COUT,int KW,bool BF16OUT>
__global__ __launch_bounds__(256) void k_conv(
    const float* __restrict__ in, const float* __restrict__ w,
    const float* __restrict__ bias, void* __restrict__ outp,
    int Lin_, int Lout_)
{
  int g = blockIdx.x*256 + threadIdx.x;
  int bi = g / Lout_;
  int l  = g - bi*Lout_;
  if (bi >= B_) return;
  float acc[COUT];
#pragma unroll
  for (int o=0;o<COUT;o++) acc[o] = bias[o];
  const float* ip = in + ((size_t)bi*Lin_ + l)*CIN;
  for (int k=0;k<KW;k++){
#pragma unroll
    for (int i4=0;i4<CIN/4;i4++){
      float4 xv = *(const float4*)(ip + k*CIN + i4*4);
#pragma unroll
      for (int c=0;c<4;c++){
        float xs = (&xv.x)[c];
        int i = i4*4+c;
#pragma unroll
        for (int o=0;o<COUT;o++)
          acc[o] = fmaf(xs, w[(o*CIN + i)*KW + k], acc[o]);
      }
    }
  }
  if constexpr (BF16OUT){
    unsigned* op = (unsigned*)outp + ((size_t)bi*Lout_ + l)*(COUT/2);
#pragma unroll
    for (int o2=0;o2<COUT/2;o2++){
      unsigned lo = f2bf(fmaxf(acc[2*o2],0.f));
      unsigned hi = f2bf(fmaxf(acc[2*o2+1],0.f));
      op[o2] = lo | (hi<<16);
    }
  } else {
    float* op = (float*)outp + ((size_t)bi*Lout_ + l)*COUT;
#pragma unroll
    for (int o=0;o<COUT;o++) op[o] = fmaxf(acc[o],0.f);
  }
}

// ---------------- pack weights: [2][1024][K] fp32 -> [2][K/8][1024] bf16x8 ----------------
__global__ __launch_bounds__(256) void k_packw2(
    const float* __restrict__ w, uint4* __restrict__ wT, int K)
{
  int gid = blockIdx.x*256 + threadIdx.x;
  int per = (K/8)*1024;
  int d = gid / per, rem = gid - d*per;
  int j8 = rem >> 10, row = rem & 1023;
  const float* src = w + ((size_t)d*1024 + row)*K + j8*8;
  float4 a = *(const float4*)src;
  float4 b = *(const float4*)(src+4);
  uint4 o;
  o.x = f2bf(a.x) | (f2bf(a.y)<<16);
  o.y = f2bf(a.z) | (f2bf(a.w)<<16);
  o.z = f2bf(b.x) | (f2bf(b.y)<<16);
  o.w = f2bf(b.z) | (f2bf(b.w)<<16);
  wT[gid] = o;
}

// ---------------- dec1: block=(b,d), flash-style single-pass attention ----------------
// 1024 thr; thread owns 8 rows x 16 channels (parity split); online softmax in regs;
// enc read ONCE per step (L2-resident across steps); whh bf16 stream as in k_rec2.
__global__ __launch_bounds__(1024) void k_dec1c(
    const unsigned* __restrict__ enc,      // [B][L3C][16] uints (bf16 pairs, 32 ch)
    const float* __restrict__ attn_w,      // [256][32]
    const uint4* __restrict__ wihT,        // [2][4][1024] bf16x8 (K=32)
    const uint4* __restrict__ whhT,        // [2][32][1024] bf16x8 (K=256)
    const float* __restrict__ bih, const float* __restrict__ bhh,
    float* __restrict__ d2in)              // [B][60][512]
{
  int b = blockIdx.x, d = blockIdx.y, tid = threadIdx.x;
  int p = tid & 1, rb = tid >> 1;          // pair covers rows rb+512k, k=0..7
  __shared__ __align__(16) float hls[256];
  __shared__ float vl[32];
  __shared__ float red[1024];
  __shared__ float scr[512];               // [16 waves][32 ch]
  __shared__ __align__(16) float ctx[32];
  __shared__ float gls[1024];

  if (tid < 256) hls[tid] = 0.f;
  float creg = 0.f;
  float bsum = bih[(size_t)d*1024 + tid] + bhh[(size_t)d*1024 + tid];
  uint4 wpre[4];
#pragma unroll
  for (int c8=0;c8<4;c8++) wpre[c8] = wihT[(size_t)d*4096 + c8*1024 + tid];
  const uint4* whp  = whhT + (size_t)d*32768;
  const uint4* encb = (const uint4*)(enc + (size_t)b*L3C*16);   // row l = 4 uint4
  __syncthreads();

  for (int t=0; t<TDEC; t++){
    // -- phase 1: v[c] = sum_u h[u]*attn_w[u][c] --
    {
      int c = tid & 31, part = tid >> 5;
      const float* wp = attn_w + (size_t)(part*8)*32 + c;
      float s = 0.f;
#pragma unroll
      for (int k=0;k<8;k++) s = fmaf(hls[part*8+k], wp[k*32], s);
      red[tid] = s;
    }
    __syncthreads();                                 // A
    if (tid < 32){
      float v = 0.f;
#pragma unroll
      for (int q=0;q<32;q++) v += red[q*32 + tid];
      vl[tid] = v;
    }
    __syncthreads();                                 // B

    // -- phase 2: flash single pass over 8 rows (my 16 channels) --
    float vreg[16];
#pragma unroll
    for (int j=0;j<16;j++) vreg[j] = vl[p*16 + j];
    float mloc = -3.0e38f, ssum = 0.f;
    float acc[16];
#pragma unroll
    for (int j=0;j<16;j++) acc[j] = 0.f;
#pragma unroll
    for (int k=0;k<8;k++){
      int l = rb + 512*k;
      bool valid = (l < L3C);                        // k<7 always valid
      uint4 u0 = valid ? encb[(size_t)l*4 + 2*p]     : make_uint4(0,0,0,0);
      uint4 u1 = valid ? encb[(size_t)l*4 + 2*p + 1] : make_uint4(0,0,0,0);
      float r[16];
      r[0]=bfl(u0.x); r[1]=bfh(u0.x); r[2]=bfl(u0.y); r[3]=bfh(u0.y);
      r[4]=bfl(u0.z); r[5]=bfh(u0.z); r[6]=bfl(u0.w); r[7]=bfh(u0.w);
      r[8]=bfl(u1.x); r[9]=bfh(u1.x); r[10]=bfl(u1.y); r[11]=bfh(u1.y);
      r[12]=bfl(u1.z); r[13]=bfh(u1.z); r[14]=bfl(u1.w); r[15]=bfh(u1.w);
      float s = 0.f;
#pragma unroll
      for (int j=0;j<16;j++) s = fmaf(r[j], vreg[j], s);
      s += __shfl_xor(s, 1);                         // combine parity halves
      s = valid ? s : -3.0e38f;
      float mnew = fmaxf(mloc, s);
      float al = __expf(mloc - mnew);                // 1 if max unchanged
      float e  = __expf(s - mnew);                   // 0 for invalid rows
      ssum = ssum*al + ((p==0) ? e : 0.f);
#pragma unroll
      for (int j=0;j<16;j++) acc[j] = fmaf(e, r[j], acc[j]*al);
      mloc = mnew;
    }
    // block max
    float m = mloc;
#pragma unroll
    for (int off=32; off; off>>=1) m = fmaxf(m, __shfl_xor(m, off));
    if ((tid&63)==0) red[tid>>6] = m;
    __syncthreads();                                 // C
    m = red[0];
#pragma unroll
    for (int i=1;i<16;i++) m = fmaxf(m, red[i]);
    // rescale local state to global max
    float sc = __expf(mloc - m);
    ssum *= sc;
#pragma unroll
    for (int j=0;j<16;j++) acc[j] *= sc;
#pragma unroll
    for (int off=32; off; off>>=1) ssum += __shfl_xor(ssum, off);
    if ((tid&63)==0) red[16 + (tid>>6)] = ssum;
    // butterfly acc within parity class (offsets 2..32)
#pragma unroll
    for (int off=2; off<=32; off<<=1){
#pragma unroll
      for (int j=0;j<16;j++) acc[j] += __shfl_xor(acc[j], off);
    }
    if ((tid&63) < 2){
      int w = tid>>6;
#pragma unroll
      for (int j=0;j<16;j++) scr[w*32 + p*16 + j] = acc[j];
    }
    __syncthreads();                                 // D
    if (tid < 32){
      float S = 0.f;
#pragma unroll
      for (int w=0;w<16;w++) S += red[16+w];
      float s2 = 0.f;
#pragma unroll
      for (int w=0;w<16;w++) s2 += scr[w*32 + tid];
      ctx[tid] = s2 / S;
    }
    __syncthreads();                                 // E

    // -- phase 3: LSTM gates (row = tid) --
    float g = bsum;
#pragma unroll
    for (int c8=0;c8<4;c8++){
      uint4 wv = wpre[c8];
      float4 x0 = *(const float4*)&ctx[c8*8];
      float4 x1 = *(const float4*)&ctx[c8*8+4];
      g = fmaf(bfl(wv.x), x0.x, g); g = fmaf(bfh(wv.x), x0.y, g);
      g = fmaf(bfl(wv.y), x0.z, g); g = fmaf(bfh(wv.y), x0.w, g);
      g = fmaf(bfl(wv.z), x1.x, g); g = fmaf(bfh(wv.z), x1.y, g);
      g = fmaf(bfl(wv.w), x1.z, g); g = fmaf(bfh(wv.w), x1.w, g);
    }
#pragma unroll 4
    for (int j8=0;j8<32;j8++){
      uint4 wv = whp[j8*1024 + tid];
      float4 h0 = *(const float4*)&hls[j8*8];
      float4 h1 = *(const float4*)&hls[j8*8+4];
      g = fmaf(bfl(wv.x), h0.x, g); g = fmaf(bfh(wv.x), h0.y, g);
      g = fmaf(bfl(wv.y), h0.z, g); g = fmaf(bfh(wv.y), h0.w, g);
      g = fmaf(bfl(wv.z), h1.x, g); g = fmaf(bfh(wv.z), h1.y, g);
      g = fmaf(bfl(wv.w), h1.z, g); g = fmaf(bfh(wv.w), h1.w, g);
    }
    gls[tid] = g;
    __syncthreads();                                 // F
    if (tid < 256){
      float ii = sigf(gls[tid]);
      float ff = sigf(gls[256+tid]);
      float gg = tanhf(gls[512+tid]);
      float oo = sigf(gls[768+tid]);
      creg = fmaf(ff, creg, ii*gg);
      float hn = oo * tanhf(creg);
      hls[tid] = hn;
      int tout = d ? (59 - t) : t;
      d2in[((size_t)b*60 + tout)*512 + d*256 + tid] = hn;
    }
    __syncthreads();                                 // G
  }
}

// ---------------- generic fp32 GEMM ----------------
__global__ __launch_bounds__(256) void k_gemm(
    const float* __restrict__ A, const float* __restrict__ W,
    float* __restrict__ C, const float* __restrict__ b1, const float* __restrict__ b2,
    int K, int ldc, size_t sW, size_t sC, int sB)
{
  int m0 = blockIdx.x * 128, n0 = blockIdx.y * 128, z = blockIdx.z;
  const float* Wz = W + (size_t)z*sW;
  float* Cz = C + (size_t)z*sC;
  const float* b1z = b1 + (size_t)z*sB;
  const float* b2z = b2 ? (b2 + (size_t)z*sB) : nullptr;
  __shared__ __align__(16) float As[16][132];
  __shared__ __align__(16) float Bs[16][132];
  int tid = threadIdx.x;
  int tx = tid & 15, ty = tid >> 4;
  int r = tid >> 2, c4 = tid & 3;
  float acc[8][8] = {};
  for (int k0=0; k0<K; k0+=16){
#pragma unroll
    for (int h=0; h<2; h++){
      int rr = r + h*64;
      float4 av = *(const float4*)(A  + (size_t)(m0+rr)*K + k0 + c4*4);
      float4 bv = *(const float4*)(Wz + (size_t)(n0+rr)*K + k0 + c4*4);
      As[c4*4+0][rr]=av.x; As[c4*4+1][rr]=av.y; As[c4*4+2][rr]=av.z; As[c4*4+3][rr]=av.w;
      Bs[c4*4+0][rr]=bv.x; Bs[c4*4+1][rr]=bv.y; Bs[c4*4+2][rr]=bv.z; Bs[c4*4+3][rr]=bv.w;
    }
    __syncthreads();
#pragma unroll
    for (int kk=0; kk<16; kk++){
      float a[8], bb[8];
      *(float4*)&a[0]  = *(const float4*)&As[kk][ty*8];
      *(float4*)&a[4]  = *(const float4*)&As[kk][ty*8+4];
      *(float4*)&bb[0] = *(const float4*)&Bs[kk][tx*8];
      *(float4*)&bb[4] = *(const float4*)&Bs[kk][tx*8+4];
#pragma unroll
      for (int i=0;i<8;i++)
#pragma unroll
        for (int j=0;j<8;j++)
          acc[i][j] = fmaf(a[i], bb[j], acc[i][j]);
    }
    __syncthreads();
  }
  float bb1[8];
#pragma unroll
  for (int j=0;j<8;j++){
    int n = n0 + tx*8 + j;
    bb1[j] = b1z[n] + (b2z ? b2z[n] : 0.f);
  }
#pragma unroll
  for (int i=0;i<8;i++){
    int m = m0 + ty*8 + i;
    float o[8];
#pragma unroll
    for (int j=0;j<8;j++) o[j] = acc[i][j] + bb1[j];
    *(float4*)(Cz + (size_t)m*ldc + n0 + tx*8)     = *(const float4*)&o[0];
    *(float4*)(Cz + (size_t)m*ldc + n0 + tx*8 + 4) = *(const float4*)&o[4];
  }
}

// ---------------- dec2: recurrent, block = (dir, batch), 16 waves ----------------
__global__ __launch_bounds__(1024) void k_rec2(
    const float* __restrict__ xg,   // [2][64][60][1024]
    const uint4* __restrict__ wT,   // [2][32][1024] bf16x8
    float* __restrict__ out)        // [64][60][512]
{
  int b = blockIdx.x, d = blockIdx.y, tid = threadIdx.x;
  __shared__ __align__(16) float hls[256];
  __shared__ float gls[1024];
  float c = 0.f;
  if (tid < 256) hls[tid] = 0.f;
  __syncthreads();
  const uint4* wp = wT + (size_t)d*32*1024;
  const float* xp = xg + (((size_t)d*64 + b)*60)*1024;
  for (int step=0; step<TDEC; step++){
    int t = d ? (TDEC-1-step) : step;
    float g = xp[(size_t)t*1024 + tid];
#pragma unroll 4
    for (int j8=0;j8<32;j8++){
      uint4 wv = wp[j8*1024 + tid];
      float4 h0 = *(const float4*)&hls[j8*8];
      float4 h1 = *(const float4*)&hls[j8*8+4];
      g = fmaf(bfl(wv.x), h0.x, g); g = fmaf(bfh(wv.x), h0.y, g);
      g = fmaf(bfl(wv.y), h0.z, g); g = fmaf(bfh(wv.y), h0.w, g);
      g = fmaf(bfl(wv.z), h1.x, g); g = fmaf(bfh(wv.z), h1.y, g);
      g = fmaf(bfl(wv.w), h1.z, g); g = fmaf(bfh(wv.w), h1.w, g);
    }
    gls[tid] = g;
    __syncthreads();
    if (tid < 256){
      float ii = sigf(gls[tid]);
      float ff = sigf(gls[256+tid]);
      float gg = tanhf(gls[512+tid]);
      float oo = sigf(gls[768+tid]);
      c = fmaf(ff, c, ii*gg);
      float hn = oo * tanhf(c);
      hls[tid] = hn;
      out[((size_t)b*60 + t)*512 + d*256 + tid] = hn;
    }
    __syncthreads();
  }
}

extern "C" void kernel_launch(void* const* d_in, const int* in_sizes, int n_in,
                              void* d_out, int out_size, void* d_ws, size_t ws_size,
                              hipStream_t stream) {
  const float* x      = (const float*)d_in[0];
  const float* cw1    = (const float*)d_in[1];
  const float* cb1    = (const float*)d_in[2];
  const float* cw2    = (const float*)d_in[3];
  const float* cb2    = (const float*)d_in[4];
  const float* cw3    = (const float*)d_in[5];
  const float* cb3    = (const float*)d_in[6];
  const float* attn_w = (const float*)d_in[7];
  // d_in[8] attn_b: constant over softmax axis -> drops out analytically
  const float* d1_wih = (const float*)d_in[9];
  const float* d1_whh = (const float*)d_in[10];
  const float* d1_bih = (const float*)d_in[11];
  const float* d1_bhh = (const float*)d_in[12];
  const float* w2_ih0 = (const float*)d_in[13];
  const float* w2_hh0 = (const float*)d_in[14];
  const float* b2_ih0 = (const float*)d_in[15];
  const float* b2_hh0 = (const float*)d_in[16];
  const float* w2_ih1 = (const float*)d_in[17];
  const float* w2_hh1 = (const float*)d_in[18];
  const float* b2_ih1 = (const float*)d_in[19];
  const float* b2_hh1 = (const float*)d_in[20];
  const float* out_w  = (const float*)d_in[21];
  const float* out_b  = (const float*)d_in[22];

  char* ws = (char*)d_ws;
  size_t off = 0;
  unsigned* enc = (unsigned*)(ws + off); off += 16675840;          // bf16 enc, padded
  size_t off_h1 = off;
  float* h1buf = (float*)(ws + off); off += 8382464;               // (B,4093,8)
  float* h2buf = (float*)(ws + off); off += 16736256;              // (B,4086,16)
  float* d2in  = (float*)(ws + off_h1);                            // reuse: (B,60,512)
  float* l0    = (float*)(ws + off_h1 + 7864320);
  float* l1    = (float*)(ws + off_h1 + 15728640);
  uint4* wT    = (uint4*)(ws + off_h1 + 23592960);                 // 1MB dec2 pack (dead tail)
  float* xg    = (float*)(ws + off); off += 31457280;              // [2][B][60][1024]
  // dec1 packs live INSIDE the xg region (xg written only after dec1 completes)
  uint4* d1whhT = (uint4*)xg;                                      // 1 MB
  uint4* d1wihT = (uint4*)((char*)xg + 1048576);                   // +128 KB
  (void)ws_size; (void)in_sizes; (void)n_in; (void)out_size;

  // dec1 weight packs (before dec1; clobbered later by xg — fine)
  k_packw2<<<256,256,0,stream>>>(d1_whh, d1whhT, 256);
  k_packw2<<<32, 256,0,stream>>>(d1_wih, d1wihT, 32);

  int g1 = (B_*L1C + 255)/256;
  k_conv<64,8,4,false><<<g1,256,0,stream>>>(x, cw1, cb1, h1buf, 4096, L1C);
  int g2 = (B_*L2C + 255)/256;
  k_conv<8,16,8,false><<<g2,256,0,stream>>>(h1buf, cw2, cb2, h2buf, L1C, L2C);
  int g3 = (B_*L3C + 255)/256;
  k_conv<16,32,16,true><<<g3,256,0,stream>>>(h2buf, cw3, cb3, enc, L2C, L3C);

  // dec1: one plain launch, block=(b,d), enc read once per step (flash-style)
  k_dec1c<<<dim3(64,2),1024,0,stream>>>(enc, attn_w, d1wihT, d1whhT,
                                        d1_bih, d1_bhh, d2in);

  // dec2 layer 0
  k_packw2<<<256,256,0,stream>>>(w2_hh0, wT, 256);
  k_gemm<<<dim3(30,8,2),256,0,stream>>>(d2in, w2_ih0, xg, b2_ih0, b2_hh0,
                                        512, 1024, (size_t)1024*512, (size_t)3840*1024, 1024);
  k_rec2<<<dim3(64,2),1024,0,stream>>>(xg, wT, l0);
  // dec2 layer 1
  k_packw2<<<256,256,0,stream>>>(w2_hh1, wT, 256);
  k_gemm<<<dim3(30,8,2),256,0,stream>>>(l0, w2_ih1, xg, b2_ih1, b2_hh1,
                                        512, 1024, (size_t)1024*512, (size_t)3840*1024, 1024);
  k_rec2<<<dim3(64,2),1024,0,stream>>>(xg, wT, l1);
  // output projection
  k_gemm<<<dim3(30,1,1),256,0,stream>>>(l1, out_w, (float*)d_out, out_b, nullptr,
                                        512, 128, 0, 0, 0);
}